// Round 1
// baseline (79.440 us; speedup 1.0000x reference)
//
#include <hip/hip_runtime.h>
#include <math.h>

// Problem constants
#define NB 4
#define BINS 256
#define HW (512*512)

// Pass-1 decomposition
#define CHUNKS 64                      // blocks per batch
#define PIX_PER_BLOCK (HW / CHUNKS)    // 4096
#define F4_PER_THREAD (PIX_PER_BLOCK / 4 / 256)  // 4

// ws layout: Hg[NB*BINS] float counts, Sg[NB*BINS] float sum-of-y
// Pass 1: hard histogram + first moment (sum of y) per bin, per batch.
__global__ __launch_bounds__(256) void hist_moments(const float* __restrict__ y,
                                                    float* __restrict__ Hg,
                                                    float* __restrict__ Sg) {
    __shared__ float lh[BINS];
    __shared__ float ls[BINS];
    const int t = threadIdx.x;
    lh[t] = 0.0f;
    ls[t] = 0.0f;
    __syncthreads();

    const int b = blockIdx.y;
    const float4* src = reinterpret_cast<const float4*>(
        y + (size_t)b * HW + (size_t)blockIdx.x * PIX_PER_BLOCK);

#pragma unroll
    for (int i = 0; i < F4_PER_THREAD; ++i) {
        float4 v = src[t + 256 * i];
        float vals[4] = {v.x, v.y, v.z, v.w};
#pragma unroll
        for (int c = 0; c < 4; ++c) {
            float f = vals[c];
            int bin = (int)(f * 256.0f);
            bin = bin < 0 ? 0 : (bin > 255 ? 255 : bin);
            atomicAdd(&lh[bin], 1.0f);   // ds_add_f32, low contention (64 lanes / 256 bins)
            atomicAdd(&ls[bin], f);
        }
    }
    __syncthreads();
    // one global atomic per (block, bin)
    atomicAdd(&Hg[b * BINS + t], lh[t]);
    atomicAdd(&Sg[b * BINS + t], ls[t]);
}

// Pass 2: build K0/K1 tables (511 sigmoid-pair evals total), dense 256-tap
// "convolution" per (batch,bin), then entropy reduction and reciprocal.
__global__ __launch_bounds__(1024) void entropy_final(const float* __restrict__ Hg,
                                                      const float* __restrict__ Sg,
                                                      float* __restrict__ out) {
    __shared__ float K0[2 * BINS];      // entries 0..510 valid, idx = (m-j)+255
    __shared__ float K1[2 * BINS];
    __shared__ float Hs[NB * BINS];
    __shared__ float Ss[NB * BINS];
    __shared__ float red[16];

    const int t = threadIdx.x;          // 0..1023
    const float DELTA = 1.0f / 256.0f;
    const float SIGMA = 30.0f;

    if (t < 2 * BINS - 1) {
        float x = (float)(t - (BINS - 1)) * DELTA;   // c_m - c_j
        float zp = SIGMA * (x + 0.5f * DELTA);
        float zm = SIGMA * (x - 0.5f * DELTA);
        float sp = 1.0f / (1.0f + __expf(-zp));
        float sm = 1.0f / (1.0f + __expf(-zm));
        K0[t] = sp - sm;                              // k(x)
        K1[t] = SIGMA * (sp * (1.0f - sp) - sm * (1.0f - sm)); // k'(x)
    }
    Hs[t] = Hg[t];
    Ss[t] = Sg[t];
    __syncthreads();

    const int b = t >> 8;               // batch
    const int j = t & 255;              // output bin
    const float* Hb = &Hs[b * BINS];
    const float* Sb = &Ss[b * BINS];

    float hist = 0.0f;
#pragma unroll 4
    for (int m = 0; m < BINS; ++m) {
        float H  = Hb[m];                              // broadcast across wave
        float M1 = Sb[m] - H * ((float)(m) + 0.5f) * DELTA;  // Σ(y - c_m)
        int idx = m - j + (BINS - 1);                  // stride-1 across lanes
        hist = fmaf(H,  K0[idx], hist);
        hist = fmaf(M1, K1[idx], hist);
    }

    float p = hist * (1.0f / (float)HW) + 1e-6f;
    float e = -p * __logf(p);

    // reduce 1024 values: wave64 shuffle reduce, then 16 partials via LDS
    const int lane = t & 63, wid = t >> 6;
    float v = e;
#pragma unroll
    for (int off = 32; off > 0; off >>= 1) v += __shfl_down(v, off);
    if (lane == 0) red[wid] = v;
    __syncthreads();
    if (t == 0) {
        float d = 0.0f;
#pragma unroll
        for (int i = 0; i < 16; ++i) d += red[i];
        out[0] = 1.0f / d;
    }
}

extern "C" void kernel_launch(void* const* d_in, const int* in_sizes, int n_in,
                              void* d_out, int out_size, void* d_ws, size_t ws_size,
                              hipStream_t stream) {
    const float* y = (const float*)d_in[0];
    float* Hg = (float*)d_ws;
    float* Sg = Hg + NB * BINS;

    // ws is poisoned 0xAA before every call — zero the accumulators each launch.
    hipMemsetAsync(d_ws, 0, 2 * NB * BINS * sizeof(float), stream);
    hist_moments<<<dim3(CHUNKS, NB), 256, 0, stream>>>(y, Hg, Sg);
    entropy_final<<<1, 1024, 0, stream>>>(Hg, Sg, (float*)d_out);
}

// Round 2
// 70.340 us; speedup vs baseline: 1.1294x; 1.1294x over previous
//
#include <hip/hip_runtime.h>
#include <math.h>

// Problem constants
#define NB 4
#define BINS 256
#define HW (512*512)

// Pass-1 decomposition
#define CHUNKS 64                      // blocks per batch
#define PIX_PER_BLOCK (HW / CHUNKS)    // 4096
#define F4_PER_THREAD (PIX_PER_BLOCK / 4 / 256)  // 4

// Pass-2 decomposition: split the 256-tap correlation over m-chunks
#define MCH 8
#define MPB (BINS / MCH)               // 32 taps per block

// ws layout: Hg[NB*BINS] counts | Sg[NB*BINS] sum-of-y | Pg[NB*BINS] soft hist

// Pass 1: hard histogram + first moment (sum of y) per bin, per batch.
__global__ __launch_bounds__(256) void hist_moments(const float* __restrict__ y,
                                                    float* __restrict__ Hg,
                                                    float* __restrict__ Sg) {
    __shared__ float lh[BINS];
    __shared__ float ls[BINS];
    const int t = threadIdx.x;
    lh[t] = 0.0f;
    ls[t] = 0.0f;
    __syncthreads();

    const int b = blockIdx.y;
    const float4* src = reinterpret_cast<const float4*>(
        y + (size_t)b * HW + (size_t)blockIdx.x * PIX_PER_BLOCK);

#pragma unroll
    for (int i = 0; i < F4_PER_THREAD; ++i) {
        float4 v = src[t + 256 * i];
        float vals[4] = {v.x, v.y, v.z, v.w};
#pragma unroll
        for (int c = 0; c < 4; ++c) {
            float f = vals[c];
            int bin = (int)(f * 256.0f);
            bin = bin < 0 ? 0 : (bin > 255 ? 255 : bin);
            atomicAdd(&lh[bin], 1.0f);
            atomicAdd(&ls[bin], f);
        }
    }
    __syncthreads();
    atomicAdd(&Hg[b * BINS + t], lh[t]);
    atomicAdd(&Sg[b * BINS + t], ls[t]);
}

// Pass 2: Taylor-expanded soft histogram as a 256-tap correlation,
// split across (m-chunk, batch) blocks so the LDS traffic spreads over 32 CUs.
// hist[b][j] = sum_m H[m]*K0[m-j] + M1[m]*K1[m-j]
__global__ __launch_bounds__(256) void conv_kernel(const float* __restrict__ Hg,
                                                   const float* __restrict__ Sg,
                                                   float* __restrict__ Pg) {
    __shared__ float2 K01[2 * BINS];   // entries 0..510 valid, idx = (m-j)+255
    __shared__ float2 HM[MPB];

    const int t = threadIdx.x;
    const int b = blockIdx.y;
    const int m0 = blockIdx.x * MPB;
    const float DELTA = 1.0f / 256.0f;
    const float SIGMA = 30.0f;

    for (int i = t; i < 2 * BINS - 1; i += 256) {
        float x = (float)(i - (BINS - 1)) * DELTA;   // c_m - c_j
        float zp = SIGMA * (x + 0.5f * DELTA);
        float zm = SIGMA * (x - 0.5f * DELTA);
        float sp = 1.0f / (1.0f + __expf(-zp));
        float sm = 1.0f / (1.0f + __expf(-zm));
        K01[i] = make_float2(sp - sm,
                             SIGMA * (sp * (1.0f - sp) - sm * (1.0f - sm)));
    }
    if (t < MPB) {
        int m = m0 + t;
        float H  = Hg[b * BINS + m];
        float M1 = Sg[b * BINS + m] - H * ((float)m + 0.5f) * DELTA; // Σ(y-c_m)
        HM[t] = make_float2(H, M1);
    }
    __syncthreads();

    const int j = t;
    float acc = 0.0f;
#pragma unroll 8
    for (int mm = 0; mm < MPB; ++mm) {
        float2 hm = HM[mm];                          // broadcast (no conflict)
        float2 k  = K01[m0 + mm - j + (BINS - 1)];   // stride-1 across lanes
        acc = fmaf(hm.x, k.x, acc);
        acc = fmaf(hm.y, k.y, acc);
    }
    atomicAdd(&Pg[b * BINS + j], acc);
}

// Pass 3: entropy reduction + reciprocal. 1024 values only — trivial.
__global__ __launch_bounds__(1024) void entropy_kernel(const float* __restrict__ Pg,
                                                       float* __restrict__ out) {
    __shared__ float red[16];
    const int t = threadIdx.x;
    float p = Pg[t] * (1.0f / (float)HW) + 1e-6f;
    float e = -p * __logf(p);
    const int lane = t & 63, wid = t >> 6;
#pragma unroll
    for (int off = 32; off > 0; off >>= 1) e += __shfl_down(e, off);
    if (lane == 0) red[wid] = e;
    __syncthreads();
    if (t == 0) {
        float d = 0.0f;
#pragma unroll
        for (int i = 0; i < 16; ++i) d += red[i];
        out[0] = 1.0f / d;
    }
}

extern "C" void kernel_launch(void* const* d_in, const int* in_sizes, int n_in,
                              void* d_out, int out_size, void* d_ws, size_t ws_size,
                              hipStream_t stream) {
    const float* y = (const float*)d_in[0];
    float* Hg = (float*)d_ws;
    float* Sg = Hg + NB * BINS;
    float* Pg = Sg + NB * BINS;

    // ws is poisoned 0xAA before every call — zero the accumulators each launch.
    hipMemsetAsync(d_ws, 0, 3 * NB * BINS * sizeof(float), stream);
    hist_moments<<<dim3(CHUNKS, NB), 256, 0, stream>>>(y, Hg, Sg);
    conv_kernel<<<dim3(MCH, NB), 256, 0, stream>>>(Hg, Sg, Pg);
    entropy_kernel<<<1, 1024, 0, stream>>>(Pg, (float*)d_out);
}